// Round 3
// baseline (10507.715 us; speedup 1.0000x reference)
//
#include <hip/hip_runtime.h>
#include <hip/hip_bf16.h>

#define H 8
#define DH 64
#define DMODEL 512
#define SEQ 408
#define BATCH 16
#define NLAYER 10
#define FFDIM 2048
#define CHUNK 68
#define NCHUNK 6
#define M (BATCH*SEQ)   // 6528
#define EPS 1e-5f

typedef __hip_bfloat16 bf16;

__device__ __forceinline__ float b2f(bf16 x){ return __bfloat162float(x); }
// mode: 0 = external tensors fp32, 1 = external tensors bf16. i is ELEMENT index.
__device__ __forceinline__ float ldin(const void* p, size_t i, int mode){
  return mode ? b2f(((const bf16*)p)[i]) : ((const float*)p)[i];
}

__global__ void detect_kernel(const void* ln1w, int* mode){
  if (threadIdx.x == 0){
    unsigned u = ((const unsigned*)ln1w)[0];   // ln1_w is all-ones: 0x3F800000 iff fp32
    *mode = (u == 0x3F800000u) ? 0 : 1;
  }
}

__global__ void embed_kernel(const int* __restrict__ tokens, const void* __restrict__ emb,
                             float* __restrict__ x, const int* __restrict__ modep){
  const int mode = *modep;
  int idx = blockIdx.x*256 + threadIdx.x;
  if (idx >= M*DMODEL) return;
  int r = idx >> 9; int d = idx & 511;
  x[idx] = ldin(emb, (size_t)tokens[r]*DMODEL + d, mode);
}

// x fp32 -> h fp32; w,b external with element offset wo
__global__ __launch_bounds__(256) void ln_kernel(const float* __restrict__ x,
    const void* __restrict__ w, const void* __restrict__ b, size_t wo,
    float* __restrict__ h, const int* __restrict__ modep){
  const int mode = *modep;
  __shared__ float red[8];
  int r = blockIdx.x, tid = threadIdx.x;
  size_t base = (size_t)r*DMODEL;
  float v0 = x[base + tid], v1 = x[base + tid + 256];
  float s = v0 + v1, s2 = v0*v0 + v1*v1;
  int lane = tid & 63, wv = tid >> 6;
  #pragma unroll
  for (int o = 32; o; o >>= 1){ s += __shfl_xor(s, o); s2 += __shfl_xor(s2, o); }
  if (lane == 0){ red[wv] = s; red[wv+4] = s2; }
  __syncthreads();
  float tot  = red[0]+red[1]+red[2]+red[3];
  float tot2 = red[4]+red[5]+red[6]+red[7];
  float mean = tot * (1.0f/512.0f);
  float var  = tot2 * (1.0f/512.0f) - mean*mean;
  float rinv = rsqrtf(var + EPS);
  h[base + tid]       = (v0-mean)*rinv*ldin(w,wo+tid,mode)     + ldin(b,wo+tid,mode);
  h[base + tid + 256] = (v1-mean)*rinv*ldin(w,wo+tid+256,mode) + ldin(b,wo+tid+256,mode);
}

// C = epi(A[M,K](fp32) @ W[K,N] + bias); W,bias external (element offsets wo,bo)
// epi: 0 none, 1 silu, 2 residual add Cin. All outputs fp32.
__global__ __launch_bounds__(256) void gemm_kernel(const float* __restrict__ A,
    const void* __restrict__ W, size_t wo, const void* __restrict__ bias, size_t bo,
    const float* Cin, float* Cout, int N, int K, int epi, const int* __restrict__ modep)
{
  const int mode = *modep;
  __shared__ __align__(16) float As[16][64];
  __shared__ __align__(16) float Ws[16][64];
  int tid = threadIdx.x;
  int tx = tid & 15, ty = tid >> 4;
  int bm = blockIdx.y * 64, bn = blockIdx.x * 64;
  float acc[4][4] = {};
  int am = tid >> 2, ak = (tid & 3) * 4;
  int wk = tid >> 4, wn = (tid & 15) * 4;
  for (int k0 = 0; k0 < K; k0 += 16){
    float4 av = *(const float4*)(A + (size_t)(bm+am)*K + k0 + ak);
    As[ak+0][am] = av.x; As[ak+1][am] = av.y;
    As[ak+2][am] = av.z; As[ak+3][am] = av.w;
    size_t wi = wo + (size_t)(k0+wk)*N + bn + wn;
    if (mode){
      ushort4 wv4 = *(const ushort4*)((const unsigned short*)W + wi);
      Ws[wk][wn+0] = __uint_as_float(((unsigned)wv4.x)<<16);
      Ws[wk][wn+1] = __uint_as_float(((unsigned)wv4.y)<<16);
      Ws[wk][wn+2] = __uint_as_float(((unsigned)wv4.z)<<16);
      Ws[wk][wn+3] = __uint_as_float(((unsigned)wv4.w)<<16);
    } else {
      float4 wv4 = *(const float4*)((const float*)W + wi);
      Ws[wk][wn+0] = wv4.x; Ws[wk][wn+1] = wv4.y;
      Ws[wk][wn+2] = wv4.z; Ws[wk][wn+3] = wv4.w;
    }
    __syncthreads();
    #pragma unroll
    for (int kk = 0; kk < 16; kk++){
      float4 a = *(const float4*)&As[kk][ty*4];
      float4 b = *(const float4*)&Ws[kk][tx*4];
      acc[0][0] += a.x*b.x; acc[0][1] += a.x*b.y; acc[0][2] += a.x*b.z; acc[0][3] += a.x*b.w;
      acc[1][0] += a.y*b.x; acc[1][1] += a.y*b.y; acc[1][2] += a.y*b.z; acc[1][3] += a.y*b.w;
      acc[2][0] += a.z*b.x; acc[2][1] += a.z*b.y; acc[2][2] += a.z*b.z; acc[2][3] += a.z*b.w;
      acc[3][0] += a.w*b.x; acc[3][1] += a.w*b.y; acc[3][2] += a.w*b.z; acc[3][3] += a.w*b.w;
    }
    __syncthreads();
  }
  #pragma unroll
  for (int i = 0; i < 4; i++){
    int m = bm + ty*4 + i;
    #pragma unroll
    for (int j = 0; j < 4; j++){
      int n = bn + tx*4 + j;
      float c = acc[i][j] + ldin(bias, bo + n, mode);
      if (epi == 1) c = c / (1.0f + expf(-c));
      if (epi == 2) c += Cin[(size_t)m*N + n];
      Cout[(size_t)m*N + n] = c;
    }
  }
}

__global__ void rope_kernel(float* __restrict__ q, float* __restrict__ k){
  int idx = blockIdx.x*256 + threadIdx.x;
  if (idx >= M*256) return;
  int r = idx >> 8, p = idx & 255;
  int hh = p >> 5, i = p & 31;
  int s = r % SEQ;
  float inv = powf(10000.0f, -(float)(2*i) * (1.0f/64.0f));
  float ang = (float)s * inv;
  float sn, c; sincosf(ang, &sn, &c);
  size_t base = (size_t)r*DMODEL + hh*64 + i;
  float q1 = q[base], q2 = q[base+32];
  q[base]    = q1*c - q2*sn;
  q[base+32] = q2*c + q1*sn;
  float k1 = k[base], k2 = k[base+32];
  const float sc = 0.125f;   // dh^-0.5
  k[base]    = (k1*c - k2*sn)*sc;
  k[base+32] = (k2*c + k1*sn)*sc;
}

__global__ __launch_bounds__(256) void retention_kernel(
    const float* __restrict__ q, const float* __restrict__ k, const float* __restrict__ v,
    float* __restrict__ ret, float* stateg)
{
  __shared__ __align__(16) float qs[CHUNK][DH];
  __shared__ __align__(16) float kT[DH][CHUNK];
  __shared__ __align__(16) float vs[CHUNK][DH];
  __shared__ float inner[34][CHUNK];
  __shared__ float gpow[CHUNK];
  int tid = threadIdx.x;
  int b = blockIdx.x >> 3, hh = blockIdx.x & 7;
  float gamma = 1.0f - exp2f(-5.0f - (float)hh);
  float* st = stateg + (size_t)blockIdx.x * (DH*DH);
  for (int e = tid; e < DH*DH; e += 256) st[e] = 0.0f;
  if (tid < CHUNK) gpow[tid] = powf(gamma, (float)tid);
  __syncthreads();
  const float chdec = gpow[CHUNK-1] * gamma;   // gamma^CHUNK

  for (int c = 0; c < NCHUNK; c++){
    size_t rowbase = ((size_t)(b*SEQ + c*CHUNK))*DMODEL + hh*DH;
    for (int e = tid; e < CHUNK*DH; e += 256){
      int i = e >> 6, d = e & 63;
      size_t g = rowbase + (size_t)i*DMODEL + d;
      qs[i][d] = q[g];
      kT[d][i] = k[g];
      vs[i][d] = v[g];
    }
    __syncthreads();
    for (int p = 0; p < 2; p++){
      int i0 = p*34;
      for (int e = tid; e < 34*CHUNK; e += 256){
        int ii = e / CHUNK, j = e - ii*CHUNK;
        int i = i0 + ii;
        float val = 0.0f;
        if (j <= i){
          float dot = 0.0f;
          #pragma unroll 16
          for (int d = 0; d < DH; d++) dot += qs[i][d] * kT[d][j];
          val = dot * gpow[i-j];
        }
        inner[ii][j] = val;
      }
      __syncthreads();
      for (int e = tid; e < 34*16; e += 256){
        int ii = e >> 4, q4 = (e & 15) * 4;
        int i = i0 + ii;
        float4 o4 = {0,0,0,0};
        for (int j = 0; j <= i; j++){
          float w = inner[ii][j];
          float4 v4 = *(const float4*)&vs[j][q4];
          o4.x += w*v4.x; o4.y += w*v4.y; o4.z += w*v4.z; o4.w += w*v4.w;
        }
        float4 c4 = {0,0,0,0};
        #pragma unroll 8
        for (int e2 = 0; e2 < DH; e2++){
          float qv = qs[i][e2];
          float4 s4 = *(const float4*)&st[e2*DH + q4];
          c4.x += qv*s4.x; c4.y += qv*s4.y; c4.z += qv*s4.z; c4.w += qv*s4.w;
        }
        float cd = gpow[i] * gamma;   // gamma^(i+1)
        size_t ob = rowbase + (size_t)i*DMODEL + q4;
        float4 o; o.x = o4.x + cd*c4.x; o.y = o4.y + cd*c4.y;
        o.z = o4.z + cd*c4.z; o.w = o4.w + cd*c4.w;
        *(float4*)&ret[ob] = o;
      }
      __syncthreads();
    }
    for (int e = tid; e < DH*16; e += 256){
      int d = e >> 4, q4 = (e & 15) * 4;
      float4 s4 = *(const float4*)&st[d*DH + q4];
      float4 a4; a4.x = s4.x*chdec; a4.y = s4.y*chdec; a4.z = s4.z*chdec; a4.w = s4.w*chdec;
      for (int j = 0; j < CHUNK; j++){
        float kj = kT[d][j] * gpow[CHUNK-1-j];
        float4 v4 = *(const float4*)&vs[j][q4];
        a4.x += kj*v4.x; a4.y += kj*v4.y; a4.z += kj*v4.z; a4.w += kj*v4.w;
      }
      *(float4*)&st[d*DH + q4] = a4;
    }
    __syncthreads();
  }
}

__global__ __launch_bounds__(512) void gnorm_gate_kernel(float* ret, const float* __restrict__ g,
    const void* __restrict__ gnw, const void* __restrict__ gnb, size_t go,
    const int* __restrict__ modep)
{
  const int mode = *modep;
  int r = blockIdx.x, tid = threadIdx.x;   // 8 waves; wave w == head w
  size_t idx = (size_t)r*DMODEL + tid;
  float val = ret[idx];
  float s = val, s2 = val*val;
  #pragma unroll
  for (int o = 32; o; o >>= 1){ s += __shfl_xor(s, o); s2 += __shfl_xor(s2, o); }
  float mean = s * (1.0f/64.0f);
  float var  = s2 * (1.0f/64.0f) - mean*mean;
  float y = (val - mean) * rsqrtf(var + EPS);
  y = y * ldin(gnw, go + tid, mode) + ldin(gnb, go + tid, mode);
  ret[idx] = y * g[idx];
}

__global__ void outwrite_kernel(const float* __restrict__ x, void* __restrict__ out,
                                const int* __restrict__ modep){
  const int mode = *modep;
  int idx = blockIdx.x*256 + threadIdx.x;
  if (idx >= M*DMODEL) return;
  if (mode) ((bf16*)out)[idx] = __float2bfloat16(x[idx]);
  else      ((float*)out)[idx] = x[idx];
}

extern "C" void kernel_launch(void* const* d_in, const int* in_sizes, int n_in,
                              void* d_out, int out_size, void* d_ws, size_t ws_size,
                              hipStream_t stream)
{
  (void)in_sizes; (void)n_in; (void)out_size; (void)ws_size;
  const int*  tokens = (const int*)d_in[0];
  const void* emb  = d_in[1];
  const void* Wq = d_in[2];  const void* bq = d_in[3];
  const void* Wk = d_in[4];  const void* bk = d_in[5];
  const void* Wv = d_in[6];  const void* bv = d_in[7];
  const void* Wg = d_in[8];  const void* bg = d_in[9];
  const void* Wo = d_in[10]; const void* bo = d_in[11];
  const void* gnw = d_in[12]; const void* gnb = d_in[13];
  const void* ln1w = d_in[14]; const void* ln1b = d_in[15];
  const void* ln2w = d_in[16]; const void* ln2b = d_in[17];
  const void* w1 = d_in[18]; const void* b1 = d_in[19];
  const void* w2 = d_in[20]; const void* b2 = d_in[21];

  const size_t MD = (size_t)M*DMODEL;
  float* xf = (float*)d_ws;   // fp32 residual [M,512]
  float* hf = xf + MD;        // LN out
  float* qf = hf + MD;
  float* kf = qf + MD;
  float* vf = kf + MD;
  float* gf = vf + MD;
  float* rf = gf + MD;        // retention out (separate, no aliasing)
  float* stg = rf + MD;       // [128,4096] retention state
  int* modep = (int*)(stg + 128*DH*DH);
  float* ff = qf;             // FFN mid [M,2048] fp32 aliases qf..gf (4*MD)

  detect_kernel<<<1, 64, 0, stream>>>(ln1w, modep);
  embed_kernel<<<(M*DMODEL)/256, 256, 0, stream>>>(tokens, emb, xf, modep);

  dim3 g512(DMODEL/64, M/64);
  dim3 gff(FFDIM/64, M/64);
  for (int l = 0; l < NLAYER; l++){
    const size_t wO = (size_t)l*DMODEL*DMODEL;
    const size_t bO = (size_t)l*DMODEL;
    const size_t w1O = (size_t)l*DMODEL*FFDIM;
    const size_t b1O = (size_t)l*FFDIM;
    ln_kernel<<<M, 256, 0, stream>>>(xf, ln1w, ln1b, bO, hf, modep);
    gemm_kernel<<<g512, 256, 0, stream>>>(hf, Wq, wO, bq, bO, nullptr, qf, DMODEL, DMODEL, 0, modep);
    gemm_kernel<<<g512, 256, 0, stream>>>(hf, Wk, wO, bk, bO, nullptr, kf, DMODEL, DMODEL, 0, modep);
    gemm_kernel<<<g512, 256, 0, stream>>>(hf, Wv, wO, bv, bO, nullptr, vf, DMODEL, DMODEL, 0, modep);
    gemm_kernel<<<g512, 256, 0, stream>>>(hf, Wg, wO, bg, bO, nullptr, gf, DMODEL, DMODEL, 1, modep);
    rope_kernel<<<M, 256, 0, stream>>>(qf, kf);
    retention_kernel<<<BATCH*H, 256, 0, stream>>>(qf, kf, vf, rf, stg);
    gnorm_gate_kernel<<<M, 512, 0, stream>>>(rf, gf, gnw, gnb, bO, modep);
    gemm_kernel<<<g512, 256, 0, stream>>>(rf, Wo, wO, bo, bO, xf, xf, DMODEL, DMODEL, 2, modep);
    ln_kernel<<<M, 256, 0, stream>>>(xf, ln2w, ln2b, bO, hf, modep);
    gemm_kernel<<<gff, 256, 0, stream>>>(hf, w1, w1O, b1, b1O, nullptr, ff, FFDIM, DMODEL, 1, modep);
    gemm_kernel<<<g512, 256, 0, stream>>>(ff, w2, w1O, b2, bO, xf, xf, DMODEL, FFDIM, 2, modep);
  }
  outwrite_kernel<<<(M*DMODEL)/256, 256, 0, stream>>>(xf, d_out, modep);
}

// Round 6
// 6840.283 us; speedup vs baseline: 1.5362x; 1.5362x over previous
//
#include <hip/hip_runtime.h>
#include <hip/hip_bf16.h>

#define H 8
#define DH 64
#define DMODEL 512
#define SEQ 408
#define BATCH 16
#define NLAYER 10
#define FFDIM 2048
#define CHUNK 68
#define NCHUNK 6
#define M (BATCH*SEQ)   // 6528
#define EPS 1e-5f

typedef __hip_bfloat16 bf16;
typedef unsigned short ushort_t;
typedef short bf8v __attribute__((ext_vector_type(8)));   // 8 bf16 bit-patterns
typedef float f4v  __attribute__((ext_vector_type(4)));

__device__ __forceinline__ float us2f(unsigned short u){ return __uint_as_float(((unsigned)u) << 16); }
__device__ __forceinline__ unsigned short f2bfs(float f){   // RNE fp32->bf16 bits
  __bf16 h = (__bf16)f;
  return *(unsigned short*)&h;
}
// split fp32 into hi+lo bf16 (combined ~16 mantissa bits)
__device__ __forceinline__ void split2(float f, unsigned short& hi, unsigned short& lo){
  hi = f2bfs(f);
  lo = f2bfs(f - us2f(hi));
}

__global__ void embed_kernel(const int* __restrict__ tokens, const float* __restrict__ emb,
                             float* __restrict__ x){
  int idx = blockIdx.x*256 + threadIdx.x;
  if (idx >= M*DMODEL) return;
  int r = idx >> 9; int d = idx & 511;
  x[idx] = emb[(size_t)tokens[r]*DMODEL + d];
}

// x fp32 -> (h_hi, h_lo) bf16 pair
__global__ __launch_bounds__(256) void ln_kernel(const float* __restrict__ x,
    const float* __restrict__ w, const float* __restrict__ b,
    ushort_t* __restrict__ hhi, ushort_t* __restrict__ hlo){
  __shared__ float red[8];
  int r = blockIdx.x, tid = threadIdx.x;
  size_t base = (size_t)r*DMODEL;
  float v0 = x[base + tid], v1 = x[base + tid + 256];
  float s = v0 + v1, s2 = v0*v0 + v1*v1;
  int lane = tid & 63, wv = tid >> 6;
  #pragma unroll
  for (int o = 32; o; o >>= 1){ s += __shfl_xor(s, o); s2 += __shfl_xor(s2, o); }
  if (lane == 0){ red[wv] = s; red[wv+4] = s2; }
  __syncthreads();
  float tot  = red[0]+red[1]+red[2]+red[3];
  float tot2 = red[4]+red[5]+red[6]+red[7];
  float mean = tot * (1.0f/512.0f);
  float var  = tot2 * (1.0f/512.0f) - mean*mean;
  float rinv = rsqrtf(var + EPS);
  float o0 = (v0-mean)*rinv*w[tid]     + b[tid];
  float o1 = (v1-mean)*rinv*w[tid+256] + b[tid+256];
  unsigned short hi, lo;
  split2(o0, hi, lo); hhi[base+tid] = hi; hlo[base+tid] = lo;
  split2(o1, hi, lo); hhi[base+tid+256] = hi; hlo[base+tid+256] = lo;
}

// ---------------- split-precision MFMA GEMM ----------------
// C = epi(A @ W + bias), A as bf16 (hi,lo) pair, W (fp32) split during staging.
// Three MFMA products: hi*hi + hi*lo + lo*hi (~fp32-accurate operands).
// epi: 0 none, 1 silu, 2 residual add Cin.
// Output: Co_hi != nullptr -> bf16 pair; else fp32 Cout.
#define BM 128
#define BN 128
#define BK 32
#define LDK 40   // padded k-stride in shorts (80 B, keeps 16B-aligned fragments)
__global__ __launch_bounds__(256) void gemm_mfma_kernel(
    const ushort_t* __restrict__ Ahi, const ushort_t* __restrict__ Alo,
    const float* __restrict__ W, const float* __restrict__ bias,
    const float* Cin, float* Cout, ushort_t* Co_hi, ushort_t* Co_lo,
    int N, int K, int epi)
{
  __shared__ __align__(16) short AsH[BM*LDK];
  __shared__ __align__(16) short AsL[BM*LDK];
  __shared__ __align__(16) short BsH[BN*LDK];
  __shared__ __align__(16) short BsL[BN*LDK];
  int tid = threadIdx.x;
  int lane = tid & 63, wave = tid >> 6;
  int wm = (wave >> 1) * 64, wn = (wave & 1) * 64;
  int l15 = lane & 15, quad = lane >> 4;
  int bm = blockIdx.y * BM, bn = blockIdx.x * BN;

  f4v acc[4][4];
  #pragma unroll
  for (int i = 0; i < 4; i++)
    #pragma unroll
    for (int j = 0; j < 4; j++) acc[i][j] = (f4v){0.f,0.f,0.f,0.f};

  int arow = tid >> 1, akseg = (tid & 1) * 16;   // A tile: 2 threads/row, 16 k each
  int bnn = tid & 127, bkseg = (tid >> 7) * 16;  // W tile: per-thread column, 16 k each

  for (int k0 = 0; k0 < K; k0 += BK){
    {
      const uint4* ap = (const uint4*)(Ahi + (size_t)(bm + arow)*K + k0 + akseg);
      uint4 a0 = ap[0], a1 = ap[1];
      *(uint4*)&AsH[arow*LDK + akseg]     = a0;
      *(uint4*)&AsH[arow*LDK + akseg + 8] = a1;
      const uint4* lp = (const uint4*)(Alo + (size_t)(bm + arow)*K + k0 + akseg);
      uint4 l0 = lp[0], l1 = lp[1];
      *(uint4*)&AsL[arow*LDK + akseg]     = l0;
      *(uint4*)&AsL[arow*LDK + akseg + 8] = l1;
    }
    size_t wbase = (size_t)(k0 + bkseg)*N + bn + bnn;
    unsigned short whi[16], wlo[16];
    #pragma unroll
    for (int i = 0; i < 16; i++) split2(W[wbase + (size_t)i*N], whi[i], wlo[i]);
    unsigned* bh = (unsigned*)&BsH[bnn*LDK + bkseg];
    unsigned* bl = (unsigned*)&BsL[bnn*LDK + bkseg];
    #pragma unroll
    for (int i = 0; i < 8; i++){
      bh[i] = (unsigned)whi[2*i] | ((unsigned)whi[2*i+1] << 16);
      bl[i] = (unsigned)wlo[2*i] | ((unsigned)wlo[2*i+1] << 16);
    }
    __syncthreads();
    bf8v afh[4], afl[4], bfh[4], bfl[4];
    #pragma unroll
    for (int t = 0; t < 4; t++){
      afh[t] = *(const bf8v*)&AsH[(wm + t*16 + l15)*LDK + quad*8];
      afl[t] = *(const bf8v*)&AsL[(wm + t*16 + l15)*LDK + quad*8];
      bfh[t] = *(const bf8v*)&BsH[(wn + t*16 + l15)*LDK + quad*8];
      bfl[t] = *(const bf8v*)&BsL[(wn + t*16 + l15)*LDK + quad*8];
    }
    #pragma unroll
    for (int i = 0; i < 4; i++)
      #pragma unroll
      for (int j = 0; j < 4; j++){
        acc[i][j] = __builtin_amdgcn_mfma_f32_16x16x32_bf16(afh[i], bfl[j], acc[i][j], 0, 0, 0);
        acc[i][j] = __builtin_amdgcn_mfma_f32_16x16x32_bf16(afl[i], bfh[j], acc[i][j], 0, 0, 0);
        acc[i][j] = __builtin_amdgcn_mfma_f32_16x16x32_bf16(afh[i], bfh[j], acc[i][j], 0, 0, 0);
      }
    __syncthreads();
  }
  // epilogue: C/D layout col = lane&15, row = quad*4 + reg  [m89/m91 verified]
  #pragma unroll
  for (int i = 0; i < 4; i++){
    int m0 = bm + wm + i*16 + quad*4;
    #pragma unroll
    for (int j = 0; j < 4; j++){
      int n = bn + wn + j*16 + l15;
      float bsv = bias[n];
      #pragma unroll
      for (int r = 0; r < 4; r++){
        int m = m0 + r;
        float c = acc[i][j][r] + bsv;
        if (epi == 1) c = c / (1.0f + expf(-c));
        if (epi == 2) c += Cin[(size_t)m*N + n];
        if (Co_hi){
          unsigned short hi, lo; split2(c, hi, lo);
          Co_hi[(size_t)m*N + n] = hi;
          Co_lo[(size_t)m*N + n] = lo;
        } else {
          Cout[(size_t)m*N + n] = c;
        }
      }
    }
  }
}

__global__ void rope_kernel(float* __restrict__ q, float* __restrict__ k){
  int idx = blockIdx.x*256 + threadIdx.x;
  if (idx >= M*256) return;
  int r = idx >> 8, p = idx & 255;
  int hh = p >> 5, i = p & 31;
  int s = r % SEQ;
  float inv = powf(10000.0f, -(float)(2*i) * (1.0f/64.0f));
  float ang = (float)s * inv;
  float sn, c; sincosf(ang, &sn, &c);
  size_t base = (size_t)r*DMODEL + hh*64 + i;
  float q1 = q[base], q2 = q[base+32];
  q[base]    = q1*c - q2*sn;
  q[base+32] = q2*c + q1*sn;
  float k1 = k[base], k2 = k[base+32];
  const float sc = 0.125f;   // dh^-0.5
  k[base]    = (k1*c - k2*sn)*sc;
  k[base+32] = (k2*c + k1*sn)*sc;
}

__global__ __launch_bounds__(256) void retention_kernel(
    const float* __restrict__ q, const float* __restrict__ k, const float* __restrict__ v,
    float* __restrict__ ret, float* stateg)
{
  __shared__ __align__(16) float qs[CHUNK][DH];
  __shared__ __align__(16) float kT[DH][CHUNK];
  __shared__ __align__(16) float vs[CHUNK][DH];
  __shared__ float inner[34][CHUNK];
  __shared__ float gpow[CHUNK];
  int tid = threadIdx.x;
  int b = blockIdx.x >> 3, hh = blockIdx.x & 7;
  float gamma = 1.0f - exp2f(-5.0f - (float)hh);
  float* st = stateg + (size_t)blockIdx.x * (DH*DH);
  for (int e = tid; e < DH*DH; e += 256) st[e] = 0.0f;
  if (tid < CHUNK) gpow[tid] = powf(gamma, (float)tid);
  __syncthreads();
  const float chdec = gpow[CHUNK-1] * gamma;   // gamma^CHUNK

  for (int c = 0; c < NCHUNK; c++){
    size_t rowbase = ((size_t)(b*SEQ + c*CHUNK))*DMODEL + hh*DH;
    for (int e = tid; e < CHUNK*DH; e += 256){
      int i = e >> 6, d = e & 63;
      size_t g = rowbase + (size_t)i*DMODEL + d;
      qs[i][d] = q[g];
      kT[d][i] = k[g];
      vs[i][d] = v[g];
    }
    __syncthreads();
    for (int p = 0; p < 2; p++){
      int i0 = p*34;
      for (int e = tid; e < 34*CHUNK; e += 256){
        int ii = e / CHUNK, j = e - ii*CHUNK;
        int i = i0 + ii;
        float val = 0.0f;
        if (j <= i){
          float dot = 0.0f;
          #pragma unroll 16
          for (int d = 0; d < DH; d++) dot += qs[i][d] * kT[d][j];
          val = dot * gpow[i-j];
        }
        inner[ii][j] = val;
      }
      __syncthreads();
      for (int e = tid; e < 34*16; e += 256){
        int ii = e >> 4, q4 = (e & 15) * 4;
        int i = i0 + ii;
        float4 o4 = {0,0,0,0};
        for (int j = 0; j <= i; j++){
          float w = inner[ii][j];
          float4 v4 = *(const float4*)&vs[j][q4];
          o4.x += w*v4.x; o4.y += w*v4.y; o4.z += w*v4.z; o4.w += w*v4.w;
        }
        float4 c4 = {0,0,0,0};
        #pragma unroll 8
        for (int e2 = 0; e2 < DH; e2++){
          float qv = qs[i][e2];
          float4 s4 = *(const float4*)&st[e2*DH + q4];
          c4.x += qv*s4.x; c4.y += qv*s4.y; c4.z += qv*s4.z; c4.w += qv*s4.w;
        }
        float cd = gpow[i] * gamma;   // gamma^(i+1)
        size_t ob = rowbase + (size_t)i*DMODEL + q4;
        float4 o; o.x = o4.x + cd*c4.x; o.y = o4.y + cd*c4.y;
        o.z = o4.z + cd*c4.z; o.w = o4.w + cd*c4.w;
        *(float4*)&ret[ob] = o;
      }
      __syncthreads();
    }
    for (int e = tid; e < DH*16; e += 256){
      int d = e >> 4, q4 = (e & 15) * 4;
      float4 s4 = *(const float4*)&st[d*DH + q4];
      float4 a4; a4.x = s4.x*chdec; a4.y = s4.y*chdec; a4.z = s4.z*chdec; a4.w = s4.w*chdec;
      for (int j = 0; j < CHUNK; j++){
        float kj = kT[d][j] * gpow[CHUNK-1-j];
        float4 v4 = *(const float4*)&vs[j][q4];
        a4.x += kj*v4.x; a4.y += kj*v4.y; a4.z += kj*v4.z; a4.w += kj*v4.w;
      }
      *(float4*)&st[d*DH + q4] = a4;
    }
    __syncthreads();
  }
}

// groupnorm (fp32 in) -> *gate -> bf16 pair out
__global__ __launch_bounds__(512) void gnorm_gate_kernel(const float* __restrict__ ret,
    const float* __restrict__ g, const float* __restrict__ gnw, const float* __restrict__ gnb,
    ushort_t* __restrict__ ohi, ushort_t* __restrict__ olo)
{
  int r = blockIdx.x, tid = threadIdx.x;   // 8 waves; wave w == head w
  size_t idx = (size_t)r*DMODEL + tid;
  float val = ret[idx];
  float s = val, s2 = val*val;
  #pragma unroll
  for (int o = 32; o; o >>= 1){ s += __shfl_xor(s, o); s2 += __shfl_xor(s2, o); }
  float mean = s * (1.0f/64.0f);
  float var  = s2 * (1.0f/64.0f) - mean*mean;
  float y = (val - mean) * rsqrtf(var + EPS);
  y = y * gnw[tid] + gnb[tid];
  y = y * g[idx];
  unsigned short hi, lo; split2(y, hi, lo);
  ohi[idx] = hi; olo[idx] = lo;
}

__global__ void outwrite_kernel(const float* __restrict__ x, float* __restrict__ out){
  int idx = blockIdx.x*256 + threadIdx.x;
  if (idx < M*DMODEL) out[idx] = x[idx];
}

extern "C" void kernel_launch(void* const* d_in, const int* in_sizes, int n_in,
                              void* d_out, int out_size, void* d_ws, size_t ws_size,
                              hipStream_t stream)
{
  (void)in_sizes; (void)n_in; (void)out_size; (void)ws_size;
  const int*   tokens = (const int*)d_in[0];
  const float* emb  = (const float*)d_in[1];
  const float* Wq = (const float*)d_in[2];  const float* bq = (const float*)d_in[3];
  const float* Wk = (const float*)d_in[4];  const float* bk = (const float*)d_in[5];
  const float* Wv = (const float*)d_in[6];  const float* bv = (const float*)d_in[7];
  const float* Wg = (const float*)d_in[8];  const float* bg = (const float*)d_in[9];
  const float* Wo = (const float*)d_in[10]; const float* bo = (const float*)d_in[11];
  const float* gnw = (const float*)d_in[12]; const float* gnb = (const float*)d_in[13];
  const float* ln1w = (const float*)d_in[14]; const float* ln1b = (const float*)d_in[15];
  const float* ln2w = (const float*)d_in[16]; const float* ln2b = (const float*)d_in[17];
  const float* w1 = (const float*)d_in[18]; const float* b1 = (const float*)d_in[19];
  const float* w2 = (const float*)d_in[20]; const float* b2 = (const float*)d_in[21];

  const size_t MD = (size_t)M*DMODEL;
  float* xf = (float*)d_ws;     // fp32 residual [M,512]
  float* qf = xf + MD;          // fp32 q
  float* kf = qf + MD;          // fp32 k
  float* vf = kf + MD;          // fp32 v
  float* gf = vf + MD;          // fp32 gate (silu'd)
  float* rf = gf + MD;          // fp32 retention out (SEPARATE buffer, no alias)
  float* stg = rf + MD;         // [128,4096] retention state (2 MB)
  ushort_t* h_hi = (ushort_t*)(stg + 128*DH*DH);  // bf16 LN-out pair [M,512]
  ushort_t* h_lo = h_hi + MD;
  // rg pair time-shares the h-pair region: h is dead between the Wg GEMM and ln2,
  // and gnorm -> Wo-GEMM -> ln2 are strictly sequential on the stream.
  ushort_t* rg_hi = h_hi;
  ushort_t* rg_lo = h_lo;
  // ff pair [M,2048] over dead q/k (hi) and v/g (lo) after gnorm consumed them.
  ushort_t* ff_hi = (ushort_t*)qf;
  ushort_t* ff_lo = (ushort_t*)vf;
  // total footprint: 6*MD fp32 + 2MB + 2*MD ushort = 95.68 MB (== round-3-proven size)

  embed_kernel<<<(M*DMODEL)/256, 256, 0, stream>>>(tokens, emb, xf);

  dim3 g512(DMODEL/BN, M/BM);   // (4, 51)
  dim3 gff(FFDIM/BN, M/BM);     // (16, 51)
  for (int l = 0; l < NLAYER; l++){
    const size_t wO = (size_t)l*DMODEL*DMODEL;
    const size_t bO = (size_t)l*DMODEL;
    const size_t w1O = (size_t)l*DMODEL*FFDIM;
    const size_t b1O = (size_t)l*FFDIM;
    ln_kernel<<<M, 256, 0, stream>>>(xf, ln1w + bO, ln1b + bO, h_hi, h_lo);
    gemm_mfma_kernel<<<g512, 256, 0, stream>>>(h_hi, h_lo, Wq + wO, bq + bO, nullptr, qf, nullptr, nullptr, DMODEL, DMODEL, 0);
    gemm_mfma_kernel<<<g512, 256, 0, stream>>>(h_hi, h_lo, Wk + wO, bk + bO, nullptr, kf, nullptr, nullptr, DMODEL, DMODEL, 0);
    gemm_mfma_kernel<<<g512, 256, 0, stream>>>(h_hi, h_lo, Wv + wO, bv + bO, nullptr, vf, nullptr, nullptr, DMODEL, DMODEL, 0);
    gemm_mfma_kernel<<<g512, 256, 0, stream>>>(h_hi, h_lo, Wg + wO, bg + bO, nullptr, gf, nullptr, nullptr, DMODEL, DMODEL, 1);
    rope_kernel<<<M, 256, 0, stream>>>(qf, kf);
    retention_kernel<<<BATCH*H, 256, 0, stream>>>(qf, kf, vf, rf, stg);
    gnorm_gate_kernel<<<M, 512, 0, stream>>>(rf, gf, gnw + bO, gnb + bO, rg_hi, rg_lo);
    gemm_mfma_kernel<<<g512, 256, 0, stream>>>(rg_hi, rg_lo, Wo + wO, bo + bO, xf, xf, nullptr, nullptr, DMODEL, DMODEL, 2);
    ln_kernel<<<M, 256, 0, stream>>>(xf, ln2w + bO, ln2b + bO, h_hi, h_lo);
    gemm_mfma_kernel<<<gff, 256, 0, stream>>>(h_hi, h_lo, w1 + w1O, b1 + b1O, nullptr, nullptr, ff_hi, ff_lo, FFDIM, DMODEL, 1);
    gemm_mfma_kernel<<<g512, 256, 0, stream>>>(ff_hi, ff_lo, w2 + w1O, b2 + bO, xf, xf, nullptr, nullptr, DMODEL, FFDIM, 2);
  }
  outwrite_kernel<<<(M*DMODEL)/256, 256, 0, stream>>>(xf, (float*)d_out);
}

// Round 7
// 5506.796 us; speedup vs baseline: 1.9081x; 1.2422x over previous
//
#include <hip/hip_runtime.h>
#include <hip/hip_bf16.h>

#define H 8
#define DH 64
#define DMODEL 512
#define SEQ 408
#define BATCH 16
#define NLAYER 10
#define FFDIM 2048
#define CHUNK 68
#define NCHUNK 6
#define M (BATCH*SEQ)   // 6528
#define EPS 1e-5f

typedef __hip_bfloat16 bf16;
typedef unsigned short ushort_t;
typedef short bf8v __attribute__((ext_vector_type(8)));   // 8 bf16 bit-patterns
typedef float f4v  __attribute__((ext_vector_type(4)));

__device__ __forceinline__ float us2f(unsigned short u){ return __uint_as_float(((unsigned)u) << 16); }
__device__ __forceinline__ unsigned short f2bfs(float f){   // RNE fp32->bf16 bits
  __bf16 h = (__bf16)f;
  return *(unsigned short*)&h;
}
// split fp32 into hi+lo bf16 (combined ~16 mantissa bits)
__device__ __forceinline__ void split2(float f, unsigned short& hi, unsigned short& lo){
  hi = f2bfs(f);
  lo = f2bfs(f - us2f(hi));
}

__global__ void embed_kernel(const int* __restrict__ tokens, const float* __restrict__ emb,
                             float* __restrict__ x){
  int idx = blockIdx.x*256 + threadIdx.x;
  if (idx >= M*DMODEL) return;
  int r = idx >> 9; int d = idx & 511;
  x[idx] = emb[(size_t)tokens[r]*DMODEL + d];
}

// x fp32 -> (h_hi, h_lo) bf16 pair
__global__ __launch_bounds__(256) void ln_kernel(const float* __restrict__ x,
    const float* __restrict__ w, const float* __restrict__ b,
    ushort_t* __restrict__ hhi, ushort_t* __restrict__ hlo){
  __shared__ float red[8];
  int r = blockIdx.x, tid = threadIdx.x;
  size_t base = (size_t)r*DMODEL;
  float v0 = x[base + tid], v1 = x[base + tid + 256];
  float s = v0 + v1, s2 = v0*v0 + v1*v1;
  int lane = tid & 63, wv = tid >> 6;
  #pragma unroll
  for (int o = 32; o; o >>= 1){ s += __shfl_xor(s, o); s2 += __shfl_xor(s2, o); }
  if (lane == 0){ red[wv] = s; red[wv+4] = s2; }
  __syncthreads();
  float tot  = red[0]+red[1]+red[2]+red[3];
  float tot2 = red[4]+red[5]+red[6]+red[7];
  float mean = tot * (1.0f/512.0f);
  float var  = tot2 * (1.0f/512.0f) - mean*mean;
  float rinv = rsqrtf(var + EPS);
  float o0 = (v0-mean)*rinv*w[tid]     + b[tid];
  float o1 = (v1-mean)*rinv*w[tid+256] + b[tid+256];
  unsigned short hi, lo;
  split2(o0, hi, lo); hhi[base+tid] = hi; hlo[base+tid] = lo;
  split2(o1, hi, lo); hhi[base+tid+256] = hi; hlo[base+tid+256] = lo;
}

// ---------------- split-precision MFMA GEMM ----------------
// C = epi(A @ W + bias), A as bf16 (hi,lo) pair, W (fp32) split during staging.
// Three MFMA products: hi*hi + hi*lo + lo*hi (~fp32-accurate operands).
// epi: 0 none, 1 silu, 2 residual add Cin.
// Output: Co_hi != nullptr -> bf16 pair; else fp32 Cout.
#define BM 128
#define BN 128
#define BK 32
#define LDK 40   // padded k-stride in shorts (80 B, keeps 16B-aligned fragments)
__global__ __launch_bounds__(256) void gemm_mfma_kernel(
    const ushort_t* __restrict__ Ahi, const ushort_t* __restrict__ Alo,
    const float* __restrict__ W, const float* __restrict__ bias,
    const float* Cin, float* Cout, ushort_t* Co_hi, ushort_t* Co_lo,
    int N, int K, int epi)
{
  __shared__ __align__(16) short AsH[BM*LDK];
  __shared__ __align__(16) short AsL[BM*LDK];
  __shared__ __align__(16) short BsH[BN*LDK];
  __shared__ __align__(16) short BsL[BN*LDK];
  int tid = threadIdx.x;
  int lane = tid & 63, wave = tid >> 6;
  int wm = (wave >> 1) * 64, wn = (wave & 1) * 64;
  int l15 = lane & 15, quad = lane >> 4;
  int bm = blockIdx.y * BM, bn = blockIdx.x * BN;

  f4v acc[4][4];
  #pragma unroll
  for (int i = 0; i < 4; i++)
    #pragma unroll
    for (int j = 0; j < 4; j++) acc[i][j] = (f4v){0.f,0.f,0.f,0.f};

  int arow = tid >> 1, akseg = (tid & 1) * 16;   // A tile: 2 threads/row, 16 k each
  int bnn = tid & 127, bkseg = (tid >> 7) * 16;  // W tile: per-thread column, 16 k each

  for (int k0 = 0; k0 < K; k0 += BK){
    {
      const uint4* ap = (const uint4*)(Ahi + (size_t)(bm + arow)*K + k0 + akseg);
      uint4 a0 = ap[0], a1 = ap[1];
      *(uint4*)&AsH[arow*LDK + akseg]     = a0;
      *(uint4*)&AsH[arow*LDK + akseg + 8] = a1;
      const uint4* lp = (const uint4*)(Alo + (size_t)(bm + arow)*K + k0 + akseg);
      uint4 l0 = lp[0], l1 = lp[1];
      *(uint4*)&AsL[arow*LDK + akseg]     = l0;
      *(uint4*)&AsL[arow*LDK + akseg + 8] = l1;
    }
    size_t wbase = (size_t)(k0 + bkseg)*N + bn + bnn;
    unsigned short whi[16], wlo[16];
    #pragma unroll
    for (int i = 0; i < 16; i++) split2(W[wbase + (size_t)i*N], whi[i], wlo[i]);
    unsigned* bh = (unsigned*)&BsH[bnn*LDK + bkseg];
    unsigned* bl = (unsigned*)&BsL[bnn*LDK + bkseg];
    #pragma unroll
    for (int i = 0; i < 8; i++){
      bh[i] = (unsigned)whi[2*i] | ((unsigned)whi[2*i+1] << 16);
      bl[i] = (unsigned)wlo[2*i] | ((unsigned)wlo[2*i+1] << 16);
    }
    __syncthreads();
    bf8v afh[4], afl[4], bfh[4], bfl[4];
    #pragma unroll
    for (int t = 0; t < 4; t++){
      afh[t] = *(const bf8v*)&AsH[(wm + t*16 + l15)*LDK + quad*8];
      afl[t] = *(const bf8v*)&AsL[(wm + t*16 + l15)*LDK + quad*8];
      bfh[t] = *(const bf8v*)&BsH[(wn + t*16 + l15)*LDK + quad*8];
      bfl[t] = *(const bf8v*)&BsL[(wn + t*16 + l15)*LDK + quad*8];
    }
    #pragma unroll
    for (int i = 0; i < 4; i++)
      #pragma unroll
      for (int j = 0; j < 4; j++){
        acc[i][j] = __builtin_amdgcn_mfma_f32_16x16x32_bf16(afh[i], bfl[j], acc[i][j], 0, 0, 0);
        acc[i][j] = __builtin_amdgcn_mfma_f32_16x16x32_bf16(afl[i], bfh[j], acc[i][j], 0, 0, 0);
        acc[i][j] = __builtin_amdgcn_mfma_f32_16x16x32_bf16(afh[i], bfh[j], acc[i][j], 0, 0, 0);
      }
    __syncthreads();
  }
  // epilogue: C/D layout col = lane&15, row = quad*4 + reg  [m89/m91 verified]
  #pragma unroll
  for (int i = 0; i < 4; i++){
    int m0 = bm + wm + i*16 + quad*4;
    #pragma unroll
    for (int j = 0; j < 4; j++){
      int n = bn + wn + j*16 + l15;
      float bsv = bias[n];
      #pragma unroll
      for (int r = 0; r < 4; r++){
        int m = m0 + r;
        float c = acc[i][j][r] + bsv;
        if (epi == 1) c = c / (1.0f + expf(-c));
        if (epi == 2) c += Cin[(size_t)m*N + n];
        if (Co_hi){
          unsigned short hi, lo; split2(c, hi, lo);
          Co_hi[(size_t)m*N + n] = hi;
          Co_lo[(size_t)m*N + n] = lo;
        } else {
          Cout[(size_t)m*N + n] = c;
        }
      }
    }
  }
}

__global__ void rope_kernel(float* __restrict__ q, float* __restrict__ k){
  int idx = blockIdx.x*256 + threadIdx.x;
  if (idx >= M*256) return;
  int r = idx >> 8, p = idx & 255;
  int hh = p >> 5, i = p & 31;
  int s = r % SEQ;
  float inv = powf(10000.0f, -(float)(2*i) * (1.0f/64.0f));
  float ang = (float)s * inv;
  float sn, c; sincosf(ang, &sn, &c);
  size_t base = (size_t)r*DMODEL + hh*64 + i;
  float q1 = q[base], q2 = q[base+32];
  q[base]    = q1*c - q2*sn;
  q[base+32] = q2*c + q1*sn;
  float k1 = k[base], k2 = k[base+32];
  const float sc = 0.125f;   // dh^-0.5
  k[base]    = (k1*c - k2*sn)*sc;
  k[base+32] = (k2*c + k1*sn)*sc;
}

// ---------------- retention, 3-phase parallel scan ----------------
// Phase 1: per-(b,h,c) chunk KV summary A_c = sum_j gamma^(C-1-j) k_j (x) v_j
__global__ __launch_bounds__(256) void ret_chunkkv_kernel(
    const float* __restrict__ k, const float* __restrict__ v, float* __restrict__ Ast)
{
  __shared__ __align__(16) float kT[DH][CHUNK];
  __shared__ __align__(16) float vs[CHUNK][DH];
  __shared__ float gpw[CHUNK];
  int tid = threadIdx.x;
  int c = blockIdx.x % NCHUNK;
  int bh = blockIdx.x / NCHUNK;
  int hh = bh & 7, b = bh >> 3;
  float gamma = 1.0f - exp2f(-5.0f - (float)hh);
  if (tid < CHUNK) gpw[tid] = powf(gamma, (float)(CHUNK-1-tid));
  size_t rowbase = ((size_t)(b*SEQ + c*CHUNK))*DMODEL + hh*DH;
  for (int e = tid; e < CHUNK*DH; e += 256){
    int i = e >> 6, d = e & 63;
    size_t g = rowbase + (size_t)i*DMODEL + d;
    kT[d][i] = k[g];
    vs[i][d] = v[g];
  }
  __syncthreads();
  float* A = Ast + (size_t)blockIdx.x * (DH*DH);
  for (int e = tid; e < DH*16; e += 256){
    int d = e >> 4, q4 = (e & 15) * 4;
    float4 a4 = {0,0,0,0};
    for (int j = 0; j < CHUNK; j++){
      float kj = kT[d][j] * gpw[j];
      float4 v4 = *(const float4*)&vs[j][q4];
      a4.x += kj*v4.x; a4.y += kj*v4.y; a4.z += kj*v4.z; a4.w += kj*v4.w;
    }
    *(float4*)&A[d*DH + q4] = a4;
  }
}

// Phase 2: per-(b,h) prefix scan over chunks, in place:
// slot c becomes state_c; state_0 = 0; state_{c+1} = state_c*gamma^C + A_c.
__global__ __launch_bounds__(256) void ret_scan_kernel(float* __restrict__ Ast)
{
  int bh = blockIdx.x, hh = bh & 7;
  float gamma = 1.0f - exp2f(-5.0f - (float)hh);
  float chdec = powf(gamma, (float)CHUNK);
  int tid = threadIdx.x;
  float4 run[4];
  #pragma unroll
  for (int t = 0; t < 4; t++) run[t] = (float4){0,0,0,0};
  size_t base = (size_t)bh * NCHUNK * (DH*DH) + (size_t)tid*16;
  for (int c = 0; c < NCHUNK; c++){
    float4* slot = (float4*)(Ast + base + (size_t)c*(DH*DH));
    float4 a[4];
    #pragma unroll
    for (int t = 0; t < 4; t++) a[t] = slot[t];
    #pragma unroll
    for (int t = 0; t < 4; t++) slot[t] = run[t];
    #pragma unroll
    for (int t = 0; t < 4; t++){
      run[t].x = run[t].x*chdec + a[t].x;
      run[t].y = run[t].y*chdec + a[t].y;
      run[t].z = run[t].z*chdec + a[t].z;
      run[t].w = run[t].w*chdec + a[t].w;
    }
  }
}

// Phase 3: per-(b,h,c) intra-chunk retention + cross term with state_c (LDS-staged)
__global__ __launch_bounds__(256) void ret_out_kernel(
    const float* __restrict__ q, const float* __restrict__ k, const float* __restrict__ v,
    const float* __restrict__ Ast, float* __restrict__ ret)
{
  __shared__ __align__(16) float qs[CHUNK][DH];
  __shared__ __align__(16) float kT[DH][CHUNK];
  __shared__ __align__(16) float vs[CHUNK][DH];
  __shared__ __align__(16) float sts[DH*DH];
  __shared__ float inner[34][CHUNK];
  __shared__ float gpw[CHUNK];
  int tid = threadIdx.x;
  int c = blockIdx.x % NCHUNK;
  int bh = blockIdx.x / NCHUNK;
  int hh = bh & 7, b = bh >> 3;
  float gamma = 1.0f - exp2f(-5.0f - (float)hh);
  if (tid < CHUNK) gpw[tid] = powf(gamma, (float)tid);
  size_t rowbase = ((size_t)(b*SEQ + c*CHUNK))*DMODEL + hh*DH;
  for (int e = tid; e < CHUNK*DH; e += 256){
    int i = e >> 6, d = e & 63;
    size_t g = rowbase + (size_t)i*DMODEL + d;
    qs[i][d] = q[g];
    kT[d][i] = k[g];
    vs[i][d] = v[g];
  }
  const float* st = Ast + (size_t)blockIdx.x * (DH*DH);
  for (int e = tid*4; e < DH*DH; e += 1024)
    *(float4*)&sts[e] = *(const float4*)&st[e];
  __syncthreads();
  for (int p = 0; p < 2; p++){
    int i0 = p*34;
    for (int e = tid; e < 34*CHUNK; e += 256){
      int ii = e / CHUNK, j = e - ii*CHUNK;
      int i = i0 + ii;
      float val = 0.0f;
      if (j <= i){
        float dot = 0.0f;
        #pragma unroll 16
        for (int d = 0; d < DH; d++) dot += qs[i][d] * kT[d][j];
        val = dot * gpw[i-j];
      }
      inner[ii][j] = val;
    }
    __syncthreads();
    for (int e = tid; e < 34*16; e += 256){
      int ii = e >> 4, q4 = (e & 15) * 4;
      int i = i0 + ii;
      float4 o4 = {0,0,0,0};
      for (int j = 0; j <= i; j++){
        float w = inner[ii][j];
        float4 v4 = *(const float4*)&vs[j][q4];
        o4.x += w*v4.x; o4.y += w*v4.y; o4.z += w*v4.z; o4.w += w*v4.w;
      }
      float4 c4 = {0,0,0,0};
      #pragma unroll 8
      for (int e2 = 0; e2 < DH; e2++){
        float qv = qs[i][e2];
        float4 s4 = *(const float4*)&sts[e2*DH + q4];
        c4.x += qv*s4.x; c4.y += qv*s4.y; c4.z += qv*s4.z; c4.w += qv*s4.w;
      }
      float cd = gpw[i] * gamma;   // gamma^(i+1)
      size_t ob = rowbase + (size_t)i*DMODEL + q4;
      float4 o; o.x = o4.x + cd*c4.x; o.y = o4.y + cd*c4.y;
      o.z = o4.z + cd*c4.z; o.w = o4.w + cd*c4.w;
      *(float4*)&ret[ob] = o;
    }
    __syncthreads();
  }
}

// groupnorm (fp32 in) -> *gate -> bf16 pair out
__global__ __launch_bounds__(512) void gnorm_gate_kernel(const float* __restrict__ ret,
    const float* __restrict__ g, const float* __restrict__ gnw, const float* __restrict__ gnb,
    ushort_t* __restrict__ ohi, ushort_t* __restrict__ olo)
{
  int r = blockIdx.x, tid = threadIdx.x;   // 8 waves; wave w == head w
  size_t idx = (size_t)r*DMODEL + tid;
  float val = ret[idx];
  float s = val, s2 = val*val;
  #pragma unroll
  for (int o = 32; o; o >>= 1){ s += __shfl_xor(s, o); s2 += __shfl_xor(s2, o); }
  float mean = s * (1.0f/64.0f);
  float var  = s2 * (1.0f/64.0f) - mean*mean;
  float y = (val - mean) * rsqrtf(var + EPS);
  y = y * gnw[tid] + gnb[tid];
  y = y * g[idx];
  unsigned short hi, lo; split2(y, hi, lo);
  ohi[idx] = hi; olo[idx] = lo;
}

__global__ void outwrite_kernel(const float* __restrict__ x, float* __restrict__ out){
  int idx = blockIdx.x*256 + threadIdx.x;
  if (idx < M*DMODEL) out[idx] = x[idx];
}

extern "C" void kernel_launch(void* const* d_in, const int* in_sizes, int n_in,
                              void* d_out, int out_size, void* d_ws, size_t ws_size,
                              hipStream_t stream)
{
  (void)in_sizes; (void)n_in; (void)out_size; (void)ws_size;
  const int*   tokens = (const int*)d_in[0];
  const float* emb  = (const float*)d_in[1];
  const float* Wq = (const float*)d_in[2];  const float* bq = (const float*)d_in[3];
  const float* Wk = (const float*)d_in[4];  const float* bk = (const float*)d_in[5];
  const float* Wv = (const float*)d_in[6];  const float* bv = (const float*)d_in[7];
  const float* Wg = (const float*)d_in[8];  const float* bg = (const float*)d_in[9];
  const float* Wo = (const float*)d_in[10]; const float* bo = (const float*)d_in[11];
  const float* gnw = (const float*)d_in[12]; const float* gnb = (const float*)d_in[13];
  const float* ln1w = (const float*)d_in[14]; const float* ln1b = (const float*)d_in[15];
  const float* ln2w = (const float*)d_in[16]; const float* ln2b = (const float*)d_in[17];
  const float* w1 = (const float*)d_in[18]; const float* b1 = (const float*)d_in[19];
  const float* w2 = (const float*)d_in[20]; const float* b2 = (const float*)d_in[21];

  const size_t MD = (size_t)M*DMODEL;
  float* xf = (float*)d_ws;     // fp32 residual [M,512]
  float* qf = xf + MD;          // fp32 q
  float* kf = qf + MD;          // fp32 k
  float* vf = kf + MD;          // fp32 v
  float* gf = vf + MD;          // fp32 gate (silu'd)
  float* rf = gf + MD;          // fp32 retention out
  ushort_t* h_hi = (ushort_t*)(rf + MD);  // bf16 LN-out pair [M,512]
  ushort_t* h_lo = h_hi + MD;
  // A/state buffer [768,4096] fp32 (12.58 MB) time-shares the h pair (13.37 MB):
  // h dead between Wg GEMM and ln2; pass1..pass3 and gnorm/Wo are stream-sequential.
  float* Ast = (float*)h_hi;
  // rg pair time-shares h too (states dead once gnorm runs).
  ushort_t* rg_hi = h_hi;
  ushort_t* rg_lo = h_lo;
  // ff pair [M,2048] over dead q/k (hi) and v/g (lo).
  ushort_t* ff_hi = (ushort_t*)qf;
  ushort_t* ff_lo = (ushort_t*)vf;
  // total footprint: 6*MD*4 + 2*MD*2 = 93.6 MB (< round-3-proven 95.7 MB)

  embed_kernel<<<(M*DMODEL)/256, 256, 0, stream>>>(tokens, emb, xf);

  dim3 g512(DMODEL/BN, M/BM);   // (4, 51)
  dim3 gff(FFDIM/BN, M/BM);     // (16, 51)
  for (int l = 0; l < NLAYER; l++){
    const size_t wO = (size_t)l*DMODEL*DMODEL;
    const size_t bO = (size_t)l*DMODEL;
    const size_t w1O = (size_t)l*DMODEL*FFDIM;
    const size_t b1O = (size_t)l*FFDIM;
    ln_kernel<<<M, 256, 0, stream>>>(xf, ln1w + bO, ln1b + bO, h_hi, h_lo);
    gemm_mfma_kernel<<<g512, 256, 0, stream>>>(h_hi, h_lo, Wq + wO, bq + bO, nullptr, qf, nullptr, nullptr, DMODEL, DMODEL, 0);
    gemm_mfma_kernel<<<g512, 256, 0, stream>>>(h_hi, h_lo, Wk + wO, bk + bO, nullptr, kf, nullptr, nullptr, DMODEL, DMODEL, 0);
    gemm_mfma_kernel<<<g512, 256, 0, stream>>>(h_hi, h_lo, Wv + wO, bv + bO, nullptr, vf, nullptr, nullptr, DMODEL, DMODEL, 0);
    gemm_mfma_kernel<<<g512, 256, 0, stream>>>(h_hi, h_lo, Wg + wO, bg + bO, nullptr, gf, nullptr, nullptr, DMODEL, DMODEL, 1);
    rope_kernel<<<M, 256, 0, stream>>>(qf, kf);
    ret_chunkkv_kernel<<<BATCH*H*NCHUNK, 256, 0, stream>>>(kf, vf, Ast);
    ret_scan_kernel<<<BATCH*H, 256, 0, stream>>>(Ast);
    ret_out_kernel<<<BATCH*H*NCHUNK, 256, 0, stream>>>(qf, kf, vf, Ast, rf);
    gnorm_gate_kernel<<<M, 512, 0, stream>>>(rf, gf, gnw + bO, gnb + bO, rg_hi, rg_lo);
    gemm_mfma_kernel<<<g512, 256, 0, stream>>>(rg_hi, rg_lo, Wo + wO, bo + bO, xf, xf, nullptr, nullptr, DMODEL, DMODEL, 2);
    ln_kernel<<<M, 256, 0, stream>>>(xf, ln2w + bO, ln2b + bO, h_hi, h_lo);
    gemm_mfma_kernel<<<gff, 256, 0, stream>>>(h_hi, h_lo, w1 + w1O, b1 + b1O, nullptr, nullptr, ff_hi, ff_lo, FFDIM, DMODEL, 1);
    gemm_mfma_kernel<<<g512, 256, 0, stream>>>(ff_hi, ff_lo, w2 + w1O, b2 + bO, xf, xf, nullptr, nullptr, DMODEL, FFDIM, 2);
  }
  outwrite_kernel<<<(M*DMODEL)/256, 256, 0, stream>>>(xf, (float*)d_out);
}

// Round 8
// 4214.656 us; speedup vs baseline: 2.4931x; 1.3066x over previous
//
#include <hip/hip_runtime.h>
#include <hip/hip_bf16.h>

#define H 8
#define DH 64
#define DMODEL 512
#define SEQ 408
#define BATCH 16
#define NLAYER 10
#define FFDIM 2048
#define CHUNK 68
#define NCHUNK 6
#define M (BATCH*SEQ)   // 6528
#define EPS 1e-5f

typedef __hip_bfloat16 bf16;
typedef unsigned short ushort_t;
typedef short bf8v __attribute__((ext_vector_type(8)));   // 8 bf16 bit-patterns
typedef float f4v  __attribute__((ext_vector_type(4)));

__device__ __forceinline__ float us2f(unsigned short u){ return __uint_as_float(((unsigned)u) << 16); }
__device__ __forceinline__ unsigned short f2bfs(float f){   // RNE fp32->bf16 bits
  __bf16 h = (__bf16)f;
  return *(unsigned short*)&h;
}
// split fp32 into hi+lo bf16 (combined ~16 mantissa bits)
__device__ __forceinline__ void split2(float f, unsigned short& hi, unsigned short& lo){
  hi = f2bfs(f);
  lo = f2bfs(f - us2f(hi));
}

__global__ void embed_kernel(const int* __restrict__ tokens, const float* __restrict__ emb,
                             float* __restrict__ x){
  int idx = blockIdx.x*256 + threadIdx.x;
  if (idx >= M*DMODEL) return;
  int r = idx >> 9; int d = idx & 511;
  x[idx] = emb[(size_t)tokens[r]*DMODEL + d];
}

// x fp32 -> (h_hi, h_lo) bf16 pair
__global__ __launch_bounds__(256) void ln_kernel(const float* __restrict__ x,
    const float* __restrict__ w, const float* __restrict__ b,
    ushort_t* __restrict__ hhi, ushort_t* __restrict__ hlo){
  __shared__ float red[8];
  int r = blockIdx.x, tid = threadIdx.x;
  size_t base = (size_t)r*DMODEL;
  float v0 = x[base + tid], v1 = x[base + tid + 256];
  float s = v0 + v1, s2 = v0*v0 + v1*v1;
  int lane = tid & 63, wv = tid >> 6;
  #pragma unroll
  for (int o = 32; o; o >>= 1){ s += __shfl_xor(s, o); s2 += __shfl_xor(s2, o); }
  if (lane == 0){ red[wv] = s; red[wv+4] = s2; }
  __syncthreads();
  float tot  = red[0]+red[1]+red[2]+red[3];
  float tot2 = red[4]+red[5]+red[6]+red[7];
  float mean = tot * (1.0f/512.0f);
  float var  = tot2 * (1.0f/512.0f) - mean*mean;
  float rinv = rsqrtf(var + EPS);
  float o0 = (v0-mean)*rinv*w[tid]     + b[tid];
  float o1 = (v1-mean)*rinv*w[tid+256] + b[tid+256];
  unsigned short hi, lo;
  split2(o0, hi, lo); hhi[base+tid] = hi; hlo[base+tid] = lo;
  split2(o1, hi, lo); hhi[base+tid+256] = hi; hlo[base+tid+256] = lo;
}

// ---------------- split-precision MFMA GEMM (templated on BM) ----------------
// C = epi(A @ W + bias), A as bf16 (hi,lo) pair, W (fp32) split during staging.
// Three MFMA products: hi*hi + hi*lo + lo*hi (~fp32-accurate operands).
// epi: 0 none, 1 silu, 2 residual add Cin.
// Output: Co_hi != nullptr -> bf16 pair; else fp32 Cout.
#define BN 128
#define BK 32
#define LDK 40   // padded k-stride in shorts (80 B, keeps 16B-aligned fragments)

template<int TBM>
__global__ __launch_bounds__(256) void gemm_mfma_kernel(
    const ushort_t* __restrict__ Ahi, const ushort_t* __restrict__ Alo,
    const float* __restrict__ W, const float* __restrict__ bias,
    const float* Cin, float* Cout, ushort_t* Co_hi, ushort_t* Co_lo,
    int N, int K, int epi)
{
  constexpr int TM = TBM/32;   // 16-row m-tiles per wave
  __shared__ __align__(16) short AsH[TBM*LDK];
  __shared__ __align__(16) short AsL[TBM*LDK];
  __shared__ __align__(16) short BsH[BN*LDK];
  __shared__ __align__(16) short BsL[BN*LDK];
  int tid = threadIdx.x;
  int lane = tid & 63, wave = tid >> 6;
  int wm = (wave >> 1) * (TBM/2), wn = (wave & 1) * 64;
  int l15 = lane & 15, quad = lane >> 4;
  int bm = blockIdx.y * TBM, bn = blockIdx.x * BN;

  f4v acc[TM][4];
  #pragma unroll
  for (int i = 0; i < TM; i++)
    #pragma unroll
    for (int j = 0; j < 4; j++) acc[i][j] = (f4v){0.f,0.f,0.f,0.f};

  int arow, akseg;
  if (TBM == 128){ arow = tid >> 1; akseg = (tid & 1) * 16; }
  else           { arow = tid >> 2; akseg = (tid & 3) * 8;  }
  int bnn = tid & 127, bkseg = (tid >> 7) * 16;

  for (int k0 = 0; k0 < K; k0 += BK){
    if (TBM == 128){
      const uint4* ap = (const uint4*)(Ahi + (size_t)(bm + arow)*K + k0 + akseg);
      uint4 a0 = ap[0], a1 = ap[1];
      *(uint4*)&AsH[arow*LDK + akseg]     = a0;
      *(uint4*)&AsH[arow*LDK + akseg + 8] = a1;
      const uint4* lp = (const uint4*)(Alo + (size_t)(bm + arow)*K + k0 + akseg);
      uint4 l0 = lp[0], l1 = lp[1];
      *(uint4*)&AsL[arow*LDK + akseg]     = l0;
      *(uint4*)&AsL[arow*LDK + akseg + 8] = l1;
    } else {
      uint4 a0 = *(const uint4*)(Ahi + (size_t)(bm + arow)*K + k0 + akseg);
      *(uint4*)&AsH[arow*LDK + akseg] = a0;
      uint4 l0 = *(const uint4*)(Alo + (size_t)(bm + arow)*K + k0 + akseg);
      *(uint4*)&AsL[arow*LDK + akseg] = l0;
    }
    size_t wbase = (size_t)(k0 + bkseg)*N + bn + bnn;
    unsigned short whi[16], wlo[16];
    #pragma unroll
    for (int i = 0; i < 16; i++) split2(W[wbase + (size_t)i*N], whi[i], wlo[i]);
    unsigned* bh = (unsigned*)&BsH[bnn*LDK + bkseg];
    unsigned* bl = (unsigned*)&BsL[bnn*LDK + bkseg];
    #pragma unroll
    for (int i = 0; i < 8; i++){
      bh[i] = (unsigned)whi[2*i] | ((unsigned)whi[2*i+1] << 16);
      bl[i] = (unsigned)wlo[2*i] | ((unsigned)wlo[2*i+1] << 16);
    }
    __syncthreads();
    bf8v afh[TM], afl[TM], bfh[4], bfl[4];
    #pragma unroll
    for (int t = 0; t < TM; t++){
      afh[t] = *(const bf8v*)&AsH[(wm + t*16 + l15)*LDK + quad*8];
      afl[t] = *(const bf8v*)&AsL[(wm + t*16 + l15)*LDK + quad*8];
    }
    #pragma unroll
    for (int t = 0; t < 4; t++){
      bfh[t] = *(const bf8v*)&BsH[(wn + t*16 + l15)*LDK + quad*8];
      bfl[t] = *(const bf8v*)&BsL[(wn + t*16 + l15)*LDK + quad*8];
    }
    #pragma unroll
    for (int i = 0; i < TM; i++)
      #pragma unroll
      for (int j = 0; j < 4; j++){
        acc[i][j] = __builtin_amdgcn_mfma_f32_16x16x32_bf16(afh[i], bfl[j], acc[i][j], 0, 0, 0);
        acc[i][j] = __builtin_amdgcn_mfma_f32_16x16x32_bf16(afl[i], bfh[j], acc[i][j], 0, 0, 0);
        acc[i][j] = __builtin_amdgcn_mfma_f32_16x16x32_bf16(afh[i], bfh[j], acc[i][j], 0, 0, 0);
      }
    __syncthreads();
  }
  // epilogue: C/D layout col = lane&15, row = quad*4 + reg  [m89/m91 verified]
  #pragma unroll
  for (int i = 0; i < TM; i++){
    int m0 = bm + wm + i*16 + quad*4;
    #pragma unroll
    for (int j = 0; j < 4; j++){
      int n = bn + wn + j*16 + l15;
      float bsv = bias[n];
      #pragma unroll
      for (int r = 0; r < 4; r++){
        int m = m0 + r;
        float c = acc[i][j][r] + bsv;
        if (epi == 1) c = c / (1.0f + expf(-c));
        if (epi == 2) c += Cin[(size_t)m*N + n];
        if (Co_hi){
          unsigned short hi, lo; split2(c, hi, lo);
          Co_hi[(size_t)m*N + n] = hi;
          Co_lo[(size_t)m*N + n] = lo;
        } else {
          Cout[(size_t)m*N + n] = c;
        }
      }
    }
  }
}

// ---------------- fused Q/K/V/G GEMM: 4 weights, one dispatch ----------------
// grid (16, M/128): blockIdx.x>>2 selects weight, (blockIdx.x&3)*128 is bn.
__global__ __launch_bounds__(256) void gemm_qkvg_kernel(
    const ushort_t* __restrict__ Ahi, const ushort_t* __restrict__ Alo,
    const float* __restrict__ Wq, const float* __restrict__ Wk,
    const float* __restrict__ Wv, const float* __restrict__ Wg,
    const float* __restrict__ bq, const float* __restrict__ bk,
    const float* __restrict__ bv, const float* __restrict__ bg,
    float* __restrict__ qo, float* __restrict__ ko,
    float* __restrict__ vo, float* __restrict__ go)
{
  const int N = DMODEL, K = DMODEL;
  __shared__ __align__(16) short AsH[128*LDK];
  __shared__ __align__(16) short AsL[128*LDK];
  __shared__ __align__(16) short BsH[BN*LDK];
  __shared__ __align__(16) short BsL[BN*LDK];
  int tid = threadIdx.x;
  int lane = tid & 63, wave = tid >> 6;
  int wm = (wave >> 1) * 64, wn = (wave & 1) * 64;
  int l15 = lane & 15, quad = lane >> 4;
  int which = blockIdx.x >> 2;
  int bn = (blockIdx.x & 3) * BN;
  int bm = blockIdx.y * 128;
  const float* W    = (which==0) ? Wq : (which==1) ? Wk : (which==2) ? Wv : Wg;
  const float* bias = (which==0) ? bq : (which==1) ? bk : (which==2) ? bv : bg;
  float* out        = (which==0) ? qo : (which==1) ? ko : (which==2) ? vo : go;

  f4v acc[4][4];
  #pragma unroll
  for (int i = 0; i < 4; i++)
    #pragma unroll
    for (int j = 0; j < 4; j++) acc[i][j] = (f4v){0.f,0.f,0.f,0.f};

  int arow = tid >> 1, akseg = (tid & 1) * 16;
  int bnn = tid & 127, bkseg = (tid >> 7) * 16;

  for (int k0 = 0; k0 < K; k0 += BK){
    {
      const uint4* ap = (const uint4*)(Ahi + (size_t)(bm + arow)*K + k0 + akseg);
      uint4 a0 = ap[0], a1 = ap[1];
      *(uint4*)&AsH[arow*LDK + akseg]     = a0;
      *(uint4*)&AsH[arow*LDK + akseg + 8] = a1;
      const uint4* lp = (const uint4*)(Alo + (size_t)(bm + arow)*K + k0 + akseg);
      uint4 l0 = lp[0], l1 = lp[1];
      *(uint4*)&AsL[arow*LDK + akseg]     = l0;
      *(uint4*)&AsL[arow*LDK + akseg + 8] = l1;
    }
    size_t wbase = (size_t)(k0 + bkseg)*N + bn + bnn;
    unsigned short whi[16], wlo[16];
    #pragma unroll
    for (int i = 0; i < 16; i++) split2(W[wbase + (size_t)i*N], whi[i], wlo[i]);
    unsigned* bh = (unsigned*)&BsH[bnn*LDK + bkseg];
    unsigned* bl = (unsigned*)&BsL[bnn*LDK + bkseg];
    #pragma unroll
    for (int i = 0; i < 8; i++){
      bh[i] = (unsigned)whi[2*i] | ((unsigned)whi[2*i+1] << 16);
      bl[i] = (unsigned)wlo[2*i] | ((unsigned)wlo[2*i+1] << 16);
    }
    __syncthreads();
    bf8v afh[4], afl[4], bfh[4], bfl[4];
    #pragma unroll
    for (int t = 0; t < 4; t++){
      afh[t] = *(const bf8v*)&AsH[(wm + t*16 + l15)*LDK + quad*8];
      afl[t] = *(const bf8v*)&AsL[(wm + t*16 + l15)*LDK + quad*8];
      bfh[t] = *(const bf8v*)&BsH[(wn + t*16 + l15)*LDK + quad*8];
      bfl[t] = *(const bf8v*)&BsL[(wn + t*16 + l15)*LDK + quad*8];
    }
    #pragma unroll
    for (int i = 0; i < 4; i++)
      #pragma unroll
      for (int j = 0; j < 4; j++){
        acc[i][j] = __builtin_amdgcn_mfma_f32_16x16x32_bf16(afh[i], bfl[j], acc[i][j], 0, 0, 0);
        acc[i][j] = __builtin_amdgcn_mfma_f32_16x16x32_bf16(afl[i], bfh[j], acc[i][j], 0, 0, 0);
        acc[i][j] = __builtin_amdgcn_mfma_f32_16x16x32_bf16(afh[i], bfh[j], acc[i][j], 0, 0, 0);
      }
    __syncthreads();
  }
  #pragma unroll
  for (int i = 0; i < 4; i++){
    int m0 = bm + wm + i*16 + quad*4;
    #pragma unroll
    for (int j = 0; j < 4; j++){
      int n = bn + wn + j*16 + l15;
      float bsv = bias[n];
      #pragma unroll
      for (int r = 0; r < 4; r++){
        int m = m0 + r;
        float c = acc[i][j][r] + bsv;
        if (which == 3) c = c / (1.0f + expf(-c));   // silu on gate
        out[(size_t)m*N + n] = c;
      }
    }
  }
}

__global__ void rope_kernel(float* __restrict__ q, float* __restrict__ k){
  int idx = blockIdx.x*256 + threadIdx.x;
  if (idx >= M*256) return;
  int r = idx >> 8, p = idx & 255;
  int hh = p >> 5, i = p & 31;
  int s = r % SEQ;
  float inv = powf(10000.0f, -(float)(2*i) * (1.0f/64.0f));
  float ang = (float)s * inv;
  float sn, c; sincosf(ang, &sn, &c);
  size_t base = (size_t)r*DMODEL + hh*64 + i;
  float q1 = q[base], q2 = q[base+32];
  q[base]    = q1*c - q2*sn;
  q[base+32] = q2*c + q1*sn;
  float k1 = k[base], k2 = k[base+32];
  const float sc = 0.125f;   // dh^-0.5
  k[base]    = (k1*c - k2*sn)*sc;
  k[base+32] = (k2*c + k1*sn)*sc;
}

// ---------------- retention, 3-phase parallel scan ----------------
__global__ __launch_bounds__(256) void ret_chunkkv_kernel(
    const float* __restrict__ k, const float* __restrict__ v, float* __restrict__ Ast)
{
  __shared__ __align__(16) float kT[DH][CHUNK];
  __shared__ __align__(16) float vs[CHUNK][DH];
  __shared__ float gpw[CHUNK];
  int tid = threadIdx.x;
  int c = blockIdx.x % NCHUNK;
  int bh = blockIdx.x / NCHUNK;
  int hh = bh & 7, b = bh >> 3;
  float gamma = 1.0f - exp2f(-5.0f - (float)hh);
  if (tid < CHUNK) gpw[tid] = powf(gamma, (float)(CHUNK-1-tid));
  size_t rowbase = ((size_t)(b*SEQ + c*CHUNK))*DMODEL + hh*DH;
  for (int e = tid; e < CHUNK*DH; e += 256){
    int i = e >> 6, d = e & 63;
    size_t g = rowbase + (size_t)i*DMODEL + d;
    kT[d][i] = k[g];
    vs[i][d] = v[g];
  }
  __syncthreads();
  float* A = Ast + (size_t)blockIdx.x * (DH*DH);
  for (int e = tid; e < DH*16; e += 256){
    int d = e >> 4, q4 = (e & 15) * 4;
    float4 a4 = {0,0,0,0};
    for (int j = 0; j < CHUNK; j++){
      float kj = kT[d][j] * gpw[j];
      float4 v4 = *(const float4*)&vs[j][q4];
      a4.x += kj*v4.x; a4.y += kj*v4.y; a4.z += kj*v4.z; a4.w += kj*v4.w;
    }
    *(float4*)&A[d*DH + q4] = a4;
  }
}

__global__ __launch_bounds__(256) void ret_scan_kernel(float* __restrict__ Ast)
{
  int bh = blockIdx.x, hh = bh & 7;
  float gamma = 1.0f - exp2f(-5.0f - (float)hh);
  float chdec = powf(gamma, (float)CHUNK);
  int tid = threadIdx.x;
  float4 run[4];
  #pragma unroll
  for (int t = 0; t < 4; t++) run[t] = (float4){0,0,0,0};
  size_t base = (size_t)bh * NCHUNK * (DH*DH) + (size_t)tid*16;
  for (int c = 0; c < NCHUNK; c++){
    float4* slot = (float4*)(Ast + base + (size_t)c*(DH*DH));
    float4 a[4];
    #pragma unroll
    for (int t = 0; t < 4; t++) a[t] = slot[t];
    #pragma unroll
    for (int t = 0; t < 4; t++) slot[t] = run[t];
    #pragma unroll
    for (int t = 0; t < 4; t++){
      run[t].x = run[t].x*chdec + a[t].x;
      run[t].y = run[t].y*chdec + a[t].y;
      run[t].z = run[t].z*chdec + a[t].z;
      run[t].w = run[t].w*chdec + a[t].w;
    }
  }
}

__global__ __launch_bounds__(256) void ret_out_kernel(
    const float* __restrict__ q, const float* __restrict__ k, const float* __restrict__ v,
    const float* __restrict__ Ast, float* __restrict__ ret)
{
  __shared__ __align__(16) float qs[CHUNK][DH];
  __shared__ __align__(16) float kT[DH][CHUNK];
  __shared__ __align__(16) float vs[CHUNK][DH];
  __shared__ __align__(16) float sts[DH*DH];
  __shared__ float inner[34][CHUNK];
  __shared__ float gpw[CHUNK];
  int tid = threadIdx.x;
  int c = blockIdx.x % NCHUNK;
  int bh = blockIdx.x / NCHUNK;
  int hh = bh & 7, b = bh >> 3;
  float gamma = 1.0f - exp2f(-5.0f - (float)hh);
  if (tid < CHUNK) gpw[tid] = powf(gamma, (float)tid);
  size_t rowbase = ((size_t)(b*SEQ + c*CHUNK))*DMODEL + hh*DH;
  for (int e = tid; e < CHUNK*DH; e += 256){
    int i = e >> 6, d = e & 63;
    size_t g = rowbase + (size_t)i*DMODEL + d;
    qs[i][d] = q[g];
    kT[d][i] = k[g];
    vs[i][d] = v[g];
  }
  const float* st = Ast + (size_t)blockIdx.x * (DH*DH);
  for (int e = tid*4; e < DH*DH; e += 1024)
    *(float4*)&sts[e] = *(const float4*)&st[e];
  __syncthreads();
  for (int p = 0; p < 2; p++){
    int i0 = p*34;
    for (int e = tid; e < 34*CHUNK; e += 256){
      int ii = e / CHUNK, j = e - ii*CHUNK;
      int i = i0 + ii;
      float val = 0.0f;
      if (j <= i){
        float dot = 0.0f;
        #pragma unroll 16
        for (int d = 0; d < DH; d++) dot += qs[i][d] * kT[d][j];
        val = dot * gpw[i-j];
      }
      inner[ii][j] = val;
    }
    __syncthreads();
    for (int e = tid; e < 34*16; e += 256){
      int ii = e >> 4, q4 = (e & 15) * 4;
      int i = i0 + ii;
      float4 o4 = {0,0,0,0};
      for (int j = 0; j <= i; j++){
        float w = inner[ii][j];
        float4 v4 = *(const float4*)&vs[j][q4];
        o4.x += w*v4.x; o4.y += w*v4.y; o4.z += w*v4.z; o4.w += w*v4.w;
      }
      float4 c4 = {0,0,0,0};
      #pragma unroll 8
      for (int e2 = 0; e2 < DH; e2++){
        float qv = qs[i][e2];
        float4 s4 = *(const float4*)&sts[e2*DH + q4];
        c4.x += qv*s4.x; c4.y += qv*s4.y; c4.z += qv*s4.z; c4.w += qv*s4.w;
      }
      float cd = gpw[i] * gamma;   // gamma^(i+1)
      size_t ob = rowbase + (size_t)i*DMODEL + q4;
      float4 o; o.x = o4.x + cd*c4.x; o.y = o4.y + cd*c4.y;
      o.z = o4.z + cd*c4.z; o.w = o4.w + cd*c4.w;
      *(float4*)&ret[ob] = o;
    }
    __syncthreads();
  }
}

// groupnorm (fp32 in) -> *gate -> bf16 pair out
__global__ __launch_bounds__(512) void gnorm_gate_kernel(const float* __restrict__ ret,
    const float* __restrict__ g, const float* __restrict__ gnw, const float* __restrict__ gnb,
    ushort_t* __restrict__ ohi, ushort_t* __restrict__ olo)
{
  int r = blockIdx.x, tid = threadIdx.x;   // 8 waves; wave w == head w
  size_t idx = (size_t)r*DMODEL + tid;
  float val = ret[idx];
  float s = val, s2 = val*val;
  #pragma unroll
  for (int o = 32; o; o >>= 1){ s += __shfl_xor(s, o); s2 += __shfl_xor(s2, o); }
  float mean = s * (1.0f/64.0f);
  float var  = s2 * (1.0f/64.0f) - mean*mean;
  float y = (val - mean) * rsqrtf(var + EPS);
  y = y * gnw[tid] + gnb[tid];
  y = y * g[idx];
  unsigned short hi, lo; split2(y, hi, lo);
  ohi[idx] = hi; olo[idx] = lo;
}

__global__ void outwrite_kernel(const float* __restrict__ x, float* __restrict__ out){
  int idx = blockIdx.x*256 + threadIdx.x;
  if (idx < M*DMODEL) out[idx] = x[idx];
}

extern "C" void kernel_launch(void* const* d_in, const int* in_sizes, int n_in,
                              void* d_out, int out_size, void* d_ws, size_t ws_size,
                              hipStream_t stream)
{
  (void)in_sizes; (void)n_in; (void)out_size; (void)ws_size;
  const int*   tokens = (const int*)d_in[0];
  const float* emb  = (const float*)d_in[1];
  const float* Wq = (const float*)d_in[2];  const float* bq = (const float*)d_in[3];
  const float* Wk = (const float*)d_in[4];  const float* bk = (const float*)d_in[5];
  const float* Wv = (const float*)d_in[6];  const float* bv = (const float*)d_in[7];
  const float* Wg = (const float*)d_in[8];  const float* bg = (const float*)d_in[9];
  const float* Wo = (const float*)d_in[10]; const float* bo = (const float*)d_in[11];
  const float* gnw = (const float*)d_in[12]; const float* gnb = (const float*)d_in[13];
  const float* ln1w = (const float*)d_in[14]; const float* ln1b = (const float*)d_in[15];
  const float* ln2w = (const float*)d_in[16]; const float* ln2b = (const float*)d_in[17];
  const float* w1 = (const float*)d_in[18]; const float* b1 = (const float*)d_in[19];
  const float* w2 = (const float*)d_in[20]; const float* b2 = (const float*)d_in[21];

  const size_t MD = (size_t)M*DMODEL;
  float* xf = (float*)d_ws;     // fp32 residual [M,512]
  float* qf = xf + MD;          // fp32 q
  float* kf = qf + MD;          // fp32 k
  float* vf = kf + MD;          // fp32 v
  float* gf = vf + MD;          // fp32 gate (silu'd)
  float* rf = gf + MD;          // fp32 retention out
  ushort_t* h_hi = (ushort_t*)(rf + MD);  // bf16 LN-out pair [M,512]
  ushort_t* h_lo = h_hi + MD;
  // A/state buffer [768,4096] fp32 (12.58 MB) time-shares the h pair (13.37 MB)
  float* Ast = (float*)h_hi;
  ushort_t* rg_hi = h_hi;
  ushort_t* rg_lo = h_lo;
  ushort_t* ff_hi = (ushort_t*)qf;
  ushort_t* ff_lo = (ushort_t*)vf;
  // total footprint: 6*MD*4 + 2*MD*2 = 93.6 MB (< proven 95.7 MB)

  embed_kernel<<<(M*DMODEL)/256, 256, 0, stream>>>(tokens, emb, xf);

  dim3 gqkvg(16, M/128);          // fused QKVG: 816 blocks
  dim3 g512b(DMODEL/BN, M/64);    // BM=64 N=512 GEMMs: (4,102)=408 blocks
  dim3 gff(FFDIM/BN, M/128);      // w1: (16,51)=816 blocks
  for (int l = 0; l < NLAYER; l++){
    const size_t wO = (size_t)l*DMODEL*DMODEL;
    const size_t bO = (size_t)l*DMODEL;
    const size_t w1O = (size_t)l*DMODEL*FFDIM;
    const size_t b1O = (size_t)l*FFDIM;
    ln_kernel<<<M, 256, 0, stream>>>(xf, ln1w + bO, ln1b + bO, h_hi, h_lo);
    gemm_qkvg_kernel<<<gqkvg, 256, 0, stream>>>(h_hi, h_lo,
        Wq + wO, Wk + wO, Wv + wO, Wg + wO,
        bq + bO, bk + bO, bv + bO, bg + bO,
        qf, kf, vf, gf);
    rope_kernel<<<M, 256, 0, stream>>>(qf, kf);
    ret_chunkkv_kernel<<<BATCH*H*NCHUNK, 256, 0, stream>>>(kf, vf, Ast);
    ret_scan_kernel<<<BATCH*H, 256, 0, stream>>>(Ast);
    ret_out_kernel<<<BATCH*H*NCHUNK, 256, 0, stream>>>(qf, kf, vf, Ast, rf);
    gnorm_gate_kernel<<<M, 512, 0, stream>>>(rf, gf, gnw + bO, gnb + bO, rg_hi, rg_lo);
    gemm_mfma_kernel<64><<<g512b, 256, 0, stream>>>(rg_hi, rg_lo, Wo + wO, bo + bO, xf, xf, nullptr, nullptr, DMODEL, DMODEL, 2);
    ln_kernel<<<M, 256, 0, stream>>>(xf, ln2w + bO, ln2b + bO, h_hi, h_lo);
    gemm_mfma_kernel<128><<<gff, 256, 0, stream>>>(h_hi, h_lo, w1 + w1O, b1 + b1O, nullptr, nullptr, ff_hi, ff_lo, FFDIM, DMODEL, 1);
    gemm_mfma_kernel<64><<<g512b, 256, 0, stream>>>(ff_hi, ff_lo, w2 + w1O, b2 + bO, xf, xf, nullptr, nullptr, DMODEL, FFDIM, 2);
  }
  outwrite_kernel<<<(M*DMODEL)/256, 256, 0, stream>>>(xf, (float*)d_out);
}